// Round 14
// baseline (52.142 us; speedup 1.0000x reference)
//
#include <hip/hip_runtime.h>
#include <math.h>

#define BB 2
#define SS 192
#define DD 512
#define HH 8
#define HD 64
#define QCB 6                 // q-rows per block
#define NQC (SS / QCB)        // 32 q-chunks
#define PROJ_N (BB*HH*SS*HD)
#define SCL (0.125f * 1.44269504088896f)   // 1/sqrt(64) * log2(e)

typedef __attribute__((ext_vector_type(4))) float f32x4;
typedef _Float16 f16x8 __attribute__((ext_vector_type(8)));

// 8 f32 -> f16x8, RNE (v_cvt_f16_f32)
__device__ __forceinline__ f16x8 cvt8_f16_rne(const float* g) {
    f16x8 r;
#pragma unroll
    for (int i = 0; i < 8; ++i) r[i] = (_Float16)g[i];
    return r;
}

// ---------------------------------------------------------------------------
// Single-f16 MFMA GEMM: y = x @ W^T  (x: M x 512, W: 512 x 512, f32 in).
// 64x64 tile / block, 256 thr (4 waves, 2x2), BK=64 (8 barrier rounds),
// double-buffered f16 LDS. Per-iter compute (~8 MFMA + staging cvt) covers
// the global-load latency, so the 1-deep pipeline doesn't stall.
// ---------------------------------------------------------------------------
template <int SPLIT>
__device__ __forceinline__ void gemm_mfma_body(const float* __restrict__ x,
                                               const float* __restrict__ W,
                                               float* __restrict__ y) {
    __shared__ short Ahs[2][8 * 64 * 8];   // [buf][ec][row][8] f16: 16 KB
    __shared__ short Bhs[2][8 * 64 * 8];

    const int t = threadIdx.x;
    const int lane = t & 63, w = t >> 6;
    const int wr = w >> 1, wc = w & 1;
    const int c16 = lane & 15, q4 = lane >> 4;
    const int m0 = blockIdx.x * 64, n0 = blockIdx.y * 64;
    const int r = t >> 2, cc = t & 3;   // staging: row 0..63, quarter 0..3

    f32x4 acc[2][2];
#pragma unroll
    for (int a = 0; a < 2; ++a)
#pragma unroll
        for (int b = 0; b < 2; ++b) acc[a][b] = (f32x4){0.f, 0.f, 0.f, 0.f};

#define STAGE(kk, bf)                                                               \
    {                                                                               \
        _Pragma("unroll") for (int h2 = 0; h2 < 2; ++h2) {                          \
            const int ec = cc * 2 + h2;                                             \
            float a8[8], w8[8];                                                     \
            *(f32x4*)&a8[0] = *(const f32x4*)&x[(m0 + r) * 512 + (kk) + ec * 8];    \
            *(f32x4*)&a8[4] = *(const f32x4*)&x[(m0 + r) * 512 + (kk) + ec * 8 + 4];\
            *(f32x4*)&w8[0] = *(const f32x4*)&W[(n0 + r) * 512 + (kk) + ec * 8];    \
            *(f32x4*)&w8[4] = *(const f32x4*)&W[(n0 + r) * 512 + (kk) + ec * 8 + 4];\
            *(f16x8*)&Ahs[bf][(ec * 64 + r) * 8] = cvt8_f16_rne(a8);                \
            *(f16x8*)&Bhs[bf][(ec * 64 + r) * 8] = cvt8_f16_rne(w8);                \
        }                                                                           \
    }

    STAGE(0, 0)
    for (int s = 0; s < 8; ++s) {
        __syncthreads();
        if (s + 1 < 8) STAGE((s + 1) * 64, (s + 1) & 1)
        const int b = s & 1;
        f16x8 aH[2][2], bH[2][2];
#pragma unroll
        for (int mt = 0; mt < 2; ++mt) {
            const int row = wr * 32 + mt * 16 + c16;
            aH[mt][0] = *(const f16x8*)&Ahs[b][(q4 * 64 + row) * 8];
            aH[mt][1] = *(const f16x8*)&Ahs[b][((q4 + 4) * 64 + row) * 8];
        }
#pragma unroll
        for (int nt = 0; nt < 2; ++nt) {
            const int col = wc * 32 + nt * 16 + c16;
            bH[nt][0] = *(const f16x8*)&Bhs[b][(q4 * 64 + col) * 8];
            bH[nt][1] = *(const f16x8*)&Bhs[b][((q4 + 4) * 64 + col) * 8];
        }
#pragma unroll
        for (int mt = 0; mt < 2; ++mt)
#pragma unroll
            for (int nt = 0; nt < 2; ++nt) {
                acc[mt][nt] = __builtin_amdgcn_mfma_f32_16x16x32_f16(aH[mt][0], bH[nt][0], acc[mt][nt], 0, 0, 0);
                acc[mt][nt] = __builtin_amdgcn_mfma_f32_16x16x32_f16(aH[mt][1], bH[nt][1], acc[mt][nt], 0, 0, 0);
            }
    }
#undef STAGE

#pragma unroll
    for (int mt = 0; mt < 2; ++mt)
#pragma unroll
        for (int nt = 0; nt < 2; ++nt)
#pragma unroll
            for (int j = 0; j < 4; ++j) {
                const int n_row = m0 + wr * 32 + mt * 16 + q4 * 4 + j;
                const int col = n0 + wc * 32 + nt * 16 + c16;
                const float v = acc[mt][nt][j];
                if (SPLIT) {
                    const int b = n_row / SS, s2 = n_row % SS;
                    const int h = col >> 6, e = col & 63;
                    y[((b * HH + h) * SS + s2) * HD + e] = v;
                } else {
                    y[n_row * 512 + col] = v;
                }
            }
}

__global__ __launch_bounds__(256) void proj4_kernel(
    const float* __restrict__ xq, const float* __restrict__ xk,
    const float* __restrict__ xl, const float* __restrict__ xv,
    const float* __restrict__ Wq, const float* __restrict__ Wk,
    const float* __restrict__ Wv, float* __restrict__ ws) {
    const int p = blockIdx.z;
    const float* x = (p == 0) ? xq : (p == 1) ? xk : (p == 2) ? xl : xv;
    const float* W = (p == 0) ? Wq : (p == 3) ? Wv : Wk;
    gemm_mfma_body<1>(x, W, ws + p * PROJ_N);
}

__global__ __launch_bounds__(256) void outproj_kernel(
    const float* __restrict__ att, const float* __restrict__ Wout,
    float* __restrict__ out) {
    gemm_mfma_body<0>(att, Wout, out);
}

// ---------------------------------------------------------------------------
// MFMA rank-3 attention: A (L rows) in REGISTERS, K in LDS, B per q.
// Grid 512 = 16 bh x 32 qc (QCB=6) = 2 blocks/CU. 512 thr = 8 waves
// (2 lg x 4 kg); wave covers 96 l x 48 k. Per q LDS traffic = 128 B/thread
// (6 B-frag ds_read + 2 broadcast qf) vs R13's 320 B -- the LDS pipe was
// the identified floor (A re-read 6x). Af loaded once from global (L2-hot).
// Live set ~112 regs (Af 48 + Bf 24 + qf 8 + acc 12 + misc) under the
// (512,4) 128-reg class. Tripwire: FETCH_SIZE must stay ~9.7 MB.
// ---------------------------------------------------------------------------
__global__ __launch_bounds__(512, 4) void attn3d_mfma_kernel(
    const float* __restrict__ qh, const float* __restrict__ kh,
    const float* __restrict__ lh, const float* __restrict__ vh,
    float* __restrict__ att) {
    __shared__ short Kf16[8][193][8];       // [ec][k(+pad)][8] f16: 24.7 KB
    __shared__ short qpk[QCB][8][8];        // [q][ec][8] f16: 768 B
    __shared__ float partial[2][QCB][196];  // [lg][q][k(+pad)]: 9.4 KB
    __shared__ float Wt[QCB][192];          // 4.6 KB
    __shared__ float zinv[QCB];

    const int blk = blockIdx.x;
    const int bh = blk >> 5, qc = blk & 31;
    const int t = threadIdx.x;
    const int lane = t & 63, w = t >> 6;
    const int lg = w >> 2, kg = w & 3;
    const int c = lane & 15, eh = lane >> 4;

    // ---- stage q rows as f16 (scale+log2e folded) ----
    if (t < QCB * 64) {
        const int q = t >> 6, e = t & 63;
        const float v = qh[(bh * SS + qc * QCB + q) * HD + e] * SCL;
        qpk[q][e >> 3][e & 7] = __builtin_bit_cast(short, (_Float16)v);
    }
    // ---- stage K as f16 frag-major (coalesced global reads) ----
#pragma unroll
    for (int j = 0; j < 3; ++j) {
        const int cid = t + 512 * j;          // 1536 8-elem chunks
        const int k = cid >> 3, ec = cid & 7;
        float b8[8];
        const float* kp = &kh[(bh * SS + k) * HD + ec * 8];
        *(f32x4*)&b8[0] = *(const f32x4*)&kp[0];
        *(f32x4*)&b8[4] = *(const f32x4*)&kp[4];
        *(f16x8*)&Kf16[ec][k][0] = cvt8_f16_rne(b8);
    }
    // ---- A fragments: L rows f16 RNE, q-invariant, in registers (global) ----
    f16x8 Af[6][2];
#pragma unroll
    for (int lt = 0; lt < 6; ++lt)
#pragma unroll
        for (int s = 0; s < 2; ++s) {
            const int row = lg * 96 + lt * 16 + c;
            float b8[8];
            const float* lp = &lh[(bh * SS + row) * HD + s * 32 + eh * 8];
            *(f32x4*)&b8[0] = *(const f32x4*)&lp[0];
            *(f32x4*)&b8[4] = *(const f32x4*)&lp[4];
            Af[lt][s] = cvt8_f16_rne(b8);
        }
    __syncthreads();   // qpk, Kf16 ready

    // ---- runtime q loop; B hoisted per q; no cross-q register state ----
    for (int q = 0; q < QCB; ++q) {
        const f16x8 qf0 = *(const f16x8*)&qpk[q][eh][0];
        const f16x8 qf1 = *(const f16x8*)&qpk[q][4 + eh][0];
        f16x8 Bf[3][2];
#pragma unroll
        for (int kt = 0; kt < 3; ++kt) {
            const int col = kg * 48 + kt * 16 + c;
            Bf[kt][0] = *(const f16x8*)&Kf16[eh][col][0] * qf0;
            Bf[kt][1] = *(const f16x8*)&Kf16[4 + eh][col][0] * qf1;
        }
        float rr0 = 0.f, rr1 = 0.f, rr2 = 0.f;
#pragma unroll
        for (int lt = 0; lt < 6; ++lt) {
            f32x4 a0 = (f32x4){0.f, 0.f, 0.f, 0.f};
            f32x4 a1 = (f32x4){0.f, 0.f, 0.f, 0.f};
            f32x4 a2 = (f32x4){0.f, 0.f, 0.f, 0.f};
            a0 = __builtin_amdgcn_mfma_f32_16x16x32_f16(Af[lt][0], Bf[0][0], a0, 0, 0, 0);
            a1 = __builtin_amdgcn_mfma_f32_16x16x32_f16(Af[lt][0], Bf[1][0], a1, 0, 0, 0);
            a2 = __builtin_amdgcn_mfma_f32_16x16x32_f16(Af[lt][0], Bf[2][0], a2, 0, 0, 0);
            a0 = __builtin_amdgcn_mfma_f32_16x16x32_f16(Af[lt][1], Bf[0][1], a0, 0, 0, 0);
            a1 = __builtin_amdgcn_mfma_f32_16x16x32_f16(Af[lt][1], Bf[1][1], a1, 0, 0, 0);
            a2 = __builtin_amdgcn_mfma_f32_16x16x32_f16(Af[lt][1], Bf[2][1], a2, 0, 0, 0);
            rr0 += (__builtin_amdgcn_exp2f(a0[0]) + __builtin_amdgcn_exp2f(a0[1])) +
                   (__builtin_amdgcn_exp2f(a0[2]) + __builtin_amdgcn_exp2f(a0[3]));
            rr1 += (__builtin_amdgcn_exp2f(a1[0]) + __builtin_amdgcn_exp2f(a1[1])) +
                   (__builtin_amdgcn_exp2f(a1[2]) + __builtin_amdgcn_exp2f(a1[3]));
            rr2 += (__builtin_amdgcn_exp2f(a2[0]) + __builtin_amdgcn_exp2f(a2[1])) +
                   (__builtin_amdgcn_exp2f(a2[2]) + __builtin_amdgcn_exp2f(a2[3]));
        }
        // 3 independent shuffle chains (ILP-overlapped)
        rr0 += __shfl_xor(rr0, 16, 64);
        rr1 += __shfl_xor(rr1, 16, 64);
        rr2 += __shfl_xor(rr2, 16, 64);
        rr0 += __shfl_xor(rr0, 32, 64);
        rr1 += __shfl_xor(rr1, 32, 64);
        rr2 += __shfl_xor(rr2, 32, 64);
        if (eh == 0) {
            partial[lg][q][kg * 48 + 0 * 16 + c] = rr0;
            partial[lg][q][kg * 48 + 1 * 16 + c] = rr1;
            partial[lg][q][kg * 48 + 2 * 16 + c] = rr2;
        }
    }
    __syncthreads();   // all partials written

    // combine lg partials
    for (int id = t; id < QCB * 192; id += 512) {
        const int q = id / 192, k = id - q * 192;
        Wt[q][k] = partial[0][q][k] + partial[1][q][k];
    }
    __syncthreads();

    // Z per q (wave w handles q = w)
    if (w < QCB) {
        const int q = w;
        float z = Wt[q][lane] + Wt[q][lane + 64] + Wt[q][lane + 128];
#pragma unroll
        for (int off = 32; off >= 1; off >>= 1) z += __shfl_xor(z, off, 64);
        if (lane == 0) zinv[q] = 1.f / z;
    }
    __syncthreads();

    // attended: att[q,d] = zinv * sum_k Wt[q][k] * vh[k,d]; 8 loads in flight
    const int b = bh >> 3, h = bh & 7;
    if (t < QCB * 64) {
        const int q = t >> 6, d = t & 63;
        const float* vp = vh + bh * SS * HD + d;
        float sum = 0.f;
        for (int k0 = 0; k0 < SS; k0 += 8) {
            float v8[8];
#pragma unroll
            for (int j = 0; j < 8; ++j) v8[j] = vp[(k0 + j) * HD];
#pragma unroll
            for (int j = 0; j < 8; ++j) sum = fmaf(Wt[q][k0 + j], v8[j], sum);
        }
        att[(b * SS + qc * QCB + q) * DD + h * HD + d] = sum * zinv[q];
    }
}

extern "C" void kernel_launch(void* const* d_in, const int* in_sizes, int n_in,
                              void* d_out, int out_size, void* d_ws, size_t ws_size,
                              hipStream_t stream) {
    (void)in_sizes; (void)n_in; (void)out_size; (void)ws_size;
    const float* q    = (const float*)d_in[0];
    const float* k    = (const float*)d_in[1];
    const float* l    = (const float*)d_in[2];
    const float* v    = (const float*)d_in[3];
    const float* Wq   = (const float*)d_in[4];
    const float* Wk   = (const float*)d_in[5];
    const float* Wv   = (const float*)d_in[6];
    const float* Wout = (const float*)d_in[7];
    float* out = (float*)d_out;

    float* ws  = (float*)d_ws;
    float* qhp = ws + 0 * PROJ_N;
    float* khp = ws + 1 * PROJ_N;
    float* lhp = ws + 2 * PROJ_N;
    float* vhp = ws + 3 * PROJ_N;
    float* atp = ws + 4 * PROJ_N;

    proj4_kernel<<<dim3(384 / 64, 512 / 64, 4), 256, 0, stream>>>(
        q, k, l, v, Wq, Wk, Wv, ws);
    attn3d_mfma_kernel<<<dim3(16 * NQC), 512, 0, stream>>>(qhp, khp, lhp, vhp, atp);
    outproj_kernel<<<dim3(384 / 64, 512 / 64), 256, 0, stream>>>(atp, Wout, out);
}